// Round 6
// baseline (2299.350 us; speedup 1.0000x reference)
//
#include <hip/hip_runtime.h>
#include <stdint.h>

// Problem constants
#define BB   64
#define TT   512
#define DIN  512
#define HH   1024
#define DOUT 512

// 4 independent batch groups x 16 rows; per group 16 WGs each owning 64 cols;
// 8 waves/WG K-split (128 K each). Layer 1 runs concurrently (WGs 64..127).
//
// SYNC (round 6): per-producer-WAVE FLAGS (sc1) + PLAIN payload loads.
// r1-r5's data-is-the-flag forced every h-byte through the device-coherent
// path (sc1 bypasses L2) -> ~6 MB/step of uncacheable broadcast = the wall
// (r4 probe -8%, r5 sleep flat => BW/congestion floor, not retries).
// New protocol:
//   producer: payload stores sc1 -> wave-local s_waitcnt vmcnt(0) (acks all
//             64 lanes' stores) -> lane 0 stores flag (sc1). Per publisher
//             WAVE (rows 0-7 / 8-15 sub-flags) — no extra barrier, and
//             non-publisher waves never drain their prefetches.
//   consumer: spin on 4 flags (one dwordx4 sc1, 16B broadcast line) ->
//             PLAIN loads for the 256B payload.
// Plain-load safety: payload addresses are write-once and NEVER touched by
// any consumer before the flag (no data spin!), so no stale L1/L2 line can
// exist: the load misses to LLC which holds the final value (flag ordering).
// First consumer per XCD fills L2; ~3 more consumers on that XCD HIT L2.
// Coherent bytes: ~6 MB/step -> ~2 MB/step; spin bytes -> ~64B/wave.
// Cross-launch/replay staleness: per-dispatch cache acquire invalidates
// L1/L2; flags are zeroed every launch (zero_kernel, 512 KB).
#define GROUPS        4
#define ROWS          16
#define WGS_PER_GROUP 16
#define NSLICE        64
#define THREADS       512
#define NW            8
#define PSTR          18            // LDS parts stride: uniform 2-way (free)
#define PBUF          (NW * 4 * 16 * PSTR)
#define SSTR          36            // stage stride (dwords)
// flags: [layer][group][t][slice 16][sub 2] dwords (sub = publisher wave)
#define FL_PER_T      32            // 16 slices x 2 subs
#define FLWORDS       (2 * GROUPS * TT * FL_PER_T)

typedef __attribute__((ext_vector_type(8))) short frag8;        // 8 x bf16
typedef __attribute__((ext_vector_type(4))) float f32x4;        // MFMA acc
typedef __attribute__((ext_vector_type(4))) unsigned int u32x4; // asm payload

__device__ __forceinline__ float bf2f(unsigned short u) {
  union { unsigned int i; float f; } v; v.i = ((unsigned int)u) << 16; return v.f;
}
__device__ __forceinline__ unsigned short f2bf(float f) {
  union { float f; unsigned int i; } v; v.f = f;
  unsigned int x = v.i;
  x += 0x7fffu + ((x >> 16) & 1u);   // RNE
  return (unsigned short)(x >> 16);
}
__device__ __forceinline__ frag8 ld8f32(const float* p) {
  frag8 r;
#pragma unroll
  for (int j = 0; j < 8; ++j) r[j] = (short)f2bf(p[j]);
  return r;
}

// flag spin: 4 consecutive flags (producer slices 2w,2w+1 x 2 subs) in one
// dwordx4 sc1 load (all lanes same address -> broadcast). Fused issue+wait
// in ONE asm block (r2 lesson: never split issue/wait across C++ code).
__device__ __forceinline__ void flag_spin4(const unsigned int* fp) {
  for (;;) {
    u32x4 f;
    asm volatile(
        "global_load_dwordx4 %0, %1, off sc1\n\t"
        "s_waitcnt vmcnt(0)"
        : "=&v"(f) : "v"(fp) : "memory");
    if ((f[0] & f[1] & f[2] & f[3]) != 0u) break;   // flags are 0/1
  }
}
// plain payload load: 4 x 64B chunks (compiler-managed global_load_dwordx4;
// compiler inserts its own waitcnt before use). MUST be called only after
// flag_spin4 — the asm "memory" clobber orders these loads after the spin.
__device__ __forceinline__ void ld4_plain(frag8 a[4], const unsigned short* p) {
  const frag8* q = (const frag8*)p;   // 16B-aligned (offset multiple of 8 elems)
  a[0] = q[0]; a[1] = q[4]; a[2] = q[8]; a[3] = q[12];
}
__device__ __forceinline__ void st32_sc1(unsigned int* p, unsigned int v) {
  asm volatile("global_store_dword %0, %1, off sc1" :: "v"(p), "v"(v) : "memory");
}
__device__ __forceinline__ void st128_sc1(unsigned int* p, u32x4 v) {
  asm volatile("global_store_dwordx4 %0, %1, off sc1" :: "v"(p), "v"(v) : "memory");
}
__device__ __forceinline__ void drain_vm() {
  asm volatile("s_waitcnt vmcnt(0)" ::: "memory");
}

// One RNN layer scan step-loop. L0: X = fp32 x (register-prefetched),
// state seq = h1seq. L1: X = bf16 h1seq (flag-gated), state seq = h2seq.
// S layout: [row][t][HH] bf16, write-once per location.
// flS = own layer-group flags (spin + store); flX = producer-layer flags
// for L1's x input (unused for L0).
template<int KIN, bool L0>
__device__ void scan_body(const void* Xv,
                          const float* Wih, const float* Whh,
                          const float* bih, const float* bhh,
                          unsigned short* S,
                          unsigned int* flS, const unsigned int* flX,
                          int g, int s, float* parts, unsigned int* stage)
{
  constexpr int KIT_IN = KIN / (NW * 32);   // L0: 2, L1: 4
  constexpr int KIT_HH = HH  / (NW * 32);   // 4

  const int j0  = s * NSLICE;
  const int r0  = g * ROWS;
  const int tid = threadIdx.x;
  const int w   = tid >> 6;                 // wave 0..7 (K-split)
  const int l   = tid & 63;
  const int lm  = l & 15;
  const int lq  = l >> 4;

  // ---- preload weights to VGPR frags (fp32 -> bf16 once) ----
  // B-frag: lane holds W[n = j0+nt*16+lm][k = w*(K/8) + kit*32 + lq*8 .. +7]
  frag8 wih_f[KIT_IN][4];
  frag8 whh_f[KIT_HH][4];
#pragma unroll
  for (int kit = 0; kit < KIT_IN; ++kit)
#pragma unroll
    for (int nt = 0; nt < 4; ++nt) {
      int n = j0 + nt * 16 + lm;
      int k = w * (KIN / NW) + kit * 32 + lq * 8;
      wih_f[kit][nt] = ld8f32(Wih + (size_t)n * KIN + k);
    }
#pragma unroll
  for (int kit = 0; kit < KIT_HH; ++kit)
#pragma unroll
    for (int nt = 0; nt < 4; ++nt) {
      int n = j0 + nt * 16 + lm;
      int k = w * (HH / NW) + kit * 32 + lq * 8;
      whh_f[kit][nt] = ld8f32(Whh + (size_t)n * HH + k);
    }

  // pass2: thread -> (row = tid&15, 2 contiguous cols at (tid>>4)*2)
  const int erow = tid & 15;
  const int ecg  = tid >> 4;               // 0..31
  float bias2[2];
#pragma unroll
  for (int j = 0; j < 2; ++j) {
    int c = j0 + ecg * 2 + j;
    bias2[j] = bih[c] + bhh[c];
  }
  // publisher: thread < 128 -> (row = tid>>3, 8 cols at (tid&7)*8);
  // wave 0 = rows 0..7 (sub-flag 0), wave 1 = rows 8..15 (sub-flag 1)
  const int prow = tid >> 3;
  const int pc8  = tid & 7;

  // per-lane A-frag source offset within a timestep row
  const size_t koff = (size_t)w * (KIN / NW) + (size_t)lq * 8;
  // consumer flag dword offset within a step: slices 2w..2w+1, both subs
  const int fcw = 4 * w;

  // ---- stage x(0) into registers ----
  float4 xa[2 * KIT_IN];                    // L0 fp32 prefetch
  frag8  xf[KIT_IN];                        // L1 flag-gated bf16 frags
  if constexpr (L0) {
    const float* xr = (const float*)Xv + ((size_t)(r0 + lm) * TT + 0) * KIN + koff;
#pragma unroll
    for (int kit = 0; kit < KIT_IN; ++kit) {
      xa[2 * kit]     = *(const float4*)(xr + kit * 32);
      xa[2 * kit + 1] = *(const float4*)(xr + kit * 32 + 4);
    }
  } else {
    flag_spin4(flX + 0 * FL_PER_T + fcw);
    ld4_plain(xf, (const unsigned short*)Xv
                      + ((size_t)(r0 + lm) * TT + 0) * KIN + koff);
  }

  for (int t = 0; t < TT; ++t) {
    f32x4 acc[4];
#pragma unroll
    for (int nt = 0; nt < 4; ++nt) acc[nt] = (f32x4){0.f, 0.f, 0.f, 0.f};

    // ---- 1) x-projection: register-only at step head ----
    if constexpr (L0) {
#pragma unroll
      for (int kit = 0; kit < KIT_IN; ++kit) {
        const float* f0 = (const float*)&xa[2 * kit];
        const float* f1 = (const float*)&xa[2 * kit + 1];
        frag8 a;
#pragma unroll
        for (int j = 0; j < 4; ++j) {
          a[j]     = (short)f2bf(f0[j]);
          a[4 + j] = (short)f2bf(f1[j]);
        }
#pragma unroll
        for (int nt = 0; nt < 4; ++nt)
          acc[nt] = __builtin_amdgcn_mfma_f32_16x16x32_bf16(a, wih_f[kit][nt], acc[nt], 0, 0, 0);
      }
    } else {
#pragma unroll
      for (int kit = 0; kit < KIT_IN; ++kit)
#pragma unroll
        for (int nt = 0; nt < 4; ++nt)
          acc[nt] = __builtin_amdgcn_mfma_f32_16x16x32_bf16(xf[kit], wih_f[kit][nt], acc[nt], 0, 0, 0);
    }

    // ---- 2) own-state flag spin + plain payload load + recurrence MFMAs ----
    if (t > 0) {
      flag_spin4(flS + (t - 1) * FL_PER_T + fcw);
      frag8 hf[KIT_HH];
      ld4_plain(hf, S + ((size_t)(r0 + lm) * TT + (t - 1)) * HH
                        + (size_t)w * (HH / NW) + lq * 8);
#pragma unroll
      for (int kit = 0; kit < KIT_HH; ++kit)
#pragma unroll
        for (int nt = 0; nt < 4; ++nt)
          acc[nt] = __builtin_amdgcn_mfma_f32_16x16x32_bf16(hf[kit], whh_f[kit][nt], acc[nt], 0, 0, 0);
    }

    // ---- 3) L0: issue x(t+1) prefetch AFTER the spin (never pollutes the
    // flag-detect path); lands during pass1/pass2/publish tail.
    if constexpr (L0) {
      if (t + 1 < TT) {
        const float* xr = (const float*)Xv
            + ((size_t)(r0 + lm) * TT + (t + 1)) * KIN + koff;
#pragma unroll
        for (int kit = 0; kit < KIT_IN; ++kit) {
          xa[2 * kit]     = *(const float4*)(xr + kit * 32);
          xa[2 * kit + 1] = *(const float4*)(xr + kit * 32 + 4);
        }
      }
    }

    // ---- 4) pass1: K-split partials to LDS (double-buffered) ----
    // C/D layout: col = lane&15, row = (lane>>4)*4 + reg  [verified m89/m91]
    float* pb = parts + (t & 1) * PBUF;
#pragma unroll
    for (int nt = 0; nt < 4; ++nt)
#pragma unroll
      for (int r = 0; r < 4; ++r)
        pb[((w * 4 + nt) * 16 + lq * 4 + r) * PSTR + lm] = acc[nt][r];
    __syncthreads();

    // ---- 5) pass2: reduce 8 K-chunks, tanh, pack 2 cols -> LDS stage ----
    unsigned int hb2 = 0;
#pragma unroll
    for (int j = 0; j < 2; ++j) {
      int c  = ecg * 2 + j;
      int nt = c >> 4;
      int lc = c & 15;
      float sm = 0.f;
#pragma unroll
      for (int w8 = 0; w8 < NW; ++w8)
        sm += pb[((w8 * 4 + nt) * 16 + erow) * PSTR + lc];
      float u = sm + bias2[j];
      float e = __expf(2.0f * u);               // tanh via exp, inf-safe
      float hv = 1.0f - 2.0f / (e + 1.0f);      // finite, |hv|<=1
      hb2 |= (unsigned int)f2bf(hv) << (16 * j);
    }
    stage[erow * SSTR + ecg] = hb2;
    __syncthreads();

    // ---- 6) publish: waves 0-1, one dwordx4 sc1 each (16B, 8 cols);
    // wave-local drain acks all 64 lanes' stores; lane 0 sets the sub-flag.
    if (tid < 128) {
      u32x4 v = *(const u32x4*)(stage + prow * SSTR + pc8 * 4);
      unsigned short* dst = S + ((size_t)(r0 + prow) * TT + t) * HH + j0 + pc8 * 8;
      st128_sc1((unsigned int*)dst, v);
      drain_vm();                       // wave-wide: all 64 lanes' stores acked
      if (l == 0)
        st32_sc1(flS + t * FL_PER_T + s * 2 + (tid >> 6), 1u);
    }
    // Waves 2-7 proceed directly into step t+1 (their polls are the sync;
    // parts[t&1] reuse at t+2 is ordered by t+1's two barriers).

    // ---- 7) L1: tail flag-gate x(t+1) = h1[t+1] (L0 runs ahead) ----
    if constexpr (!L0) {
      if (t + 1 < TT) {
        flag_spin4(flX + (t + 1) * FL_PER_T + fcw);
        ld4_plain(xf, (const unsigned short*)Xv
                          + ((size_t)(r0 + lm) * TT + (t + 1)) * KIN + koff);
      }
    }
  }
}

__global__ __launch_bounds__(THREADS, 1)
void rnn_fused(const float* x,
               const float* Wih0, const float* Whh0, const float* bih0, const float* bhh0,
               const float* Wih1, const float* Whh1, const float* bih1, const float* bhh1,
               unsigned short* h1seq, unsigned short* h2seq, unsigned int* flags)
{
  __shared__ float parts[2 * PBUF];
  __shared__ unsigned int stage[16 * SSTR];
  const int wg = blockIdx.x;
  if (wg < GROUPS * WGS_PER_GROUP) {
    const int g = wg / WGS_PER_GROUP, s = wg % WGS_PER_GROUP;
    unsigned int* fl0g = flags + (size_t)g * TT * FL_PER_T;
    scan_body<DIN, true>(x, Wih0, Whh0, bih0, bhh0, h1seq,
                         fl0g, nullptr, g, s, parts, stage);
  } else {
    const int wg2 = wg - GROUPS * WGS_PER_GROUP;
    const int g = wg2 / WGS_PER_GROUP, s = wg2 % WGS_PER_GROUP;
    unsigned int* fl0g = flags + (size_t)g * TT * FL_PER_T;
    unsigned int* fl1g = flags + (size_t)(GROUPS + g) * TT * FL_PER_T;
    scan_body<HH, false>(h1seq, Wih1, Whh1, bih1, bhh1, h2seq,
                         fl1g, fl0g, g, s, parts, stage);
  }
}

// zero the flag array every launch (write-once-per-launch protocol)
__global__ void zero_kernel(unsigned int* __restrict__ p, int n) {
  int i  = blockIdx.x * blockDim.x + threadIdx.x;
  int st = gridDim.x * blockDim.x;
  for (; i < n; i += st) p[i] = 0u;
}

// out[m][n] = h2seq[m][T-1] . Wfc[n] + bfc[n]
__global__ void fc_kernel(const unsigned short* __restrict__ h2seq,  // bf16
                          const float* __restrict__ Wfc,             // fp32
                          const float* __restrict__ bfc,             // fp32
                          float* __restrict__ out)                   // fp32
{
  int idx = blockIdx.x * blockDim.x + threadIdx.x;  // 32768 = 64*512
  int m = idx >> 9;
  int n = idx & 511;
  const unsigned short* hp = h2seq + ((size_t)m * TT + (TT - 1)) * HH;
  const float*          wp = Wfc + (size_t)n * HH;
  float acc = 0.f;
#pragma unroll 4
  for (int k = 0; k < HH; k += 4) {
    ushort4 hv = *(const ushort4*)(hp + k);
    float4  wv = *(const float4*)(wp + k);
    acc += bf2f(hv.x) * wv.x + bf2f(hv.y) * wv.y
         + bf2f(hv.z) * wv.z + bf2f(hv.w) * wv.w;
  }
  out[idx] = acc + bfc[n];
}

extern "C" void kernel_launch(void* const* d_in, const int* in_sizes, int n_in,
                              void* d_out, int out_size, void* d_ws, size_t ws_size,
                              hipStream_t stream)
{
  const float* x    = (const float*)d_in[0];
  const float* Wih0 = (const float*)d_in[1];
  const float* Whh0 = (const float*)d_in[2];
  const float* bih0 = (const float*)d_in[3];
  const float* bhh0 = (const float*)d_in[4];
  const float* Wih1 = (const float*)d_in[5];
  const float* Whh1 = (const float*)d_in[6];
  const float* bih1 = (const float*)d_in[7];
  const float* bhh1 = (const float*)d_in[8];
  const float* Wfc  = (const float*)d_in[9];
  const float* bfc  = (const float*)d_in[10];

  // ws: h1seq (64MB) | h2seq (64MB) | flags (512KB)
  unsigned char* ws = (unsigned char*)d_ws;
  unsigned short* h1seq = (unsigned short*)ws;
  unsigned short* h2seq = (unsigned short*)(ws + (size_t)BB * TT * HH * 2);
  unsigned int*   flags = (unsigned int*)(ws + 2 * (size_t)BB * TT * HH * 2);

  // zero flags (512 KB; h buffers need no poisoning — flags gate all reads)
  zero_kernel<<<64, 256, 0, stream>>>(flags, FLWORDS);

  // fused 2-layer pipelined scan: WGs 0..63 = layer 0, 64..127 = layer 1
  rnn_fused<<<2 * GROUPS * WGS_PER_GROUP, THREADS, 0, stream>>>(
      x, Wih0, Whh0, bih0, bhh0, Wih1, Whh1, bih1, bhh1, h1seq, h2seq, flags);

  fc_kernel<<<(BB * DOUT) / 256, 256, 0, stream>>>(h2seq, Wfc, bfc, (float*)d_out);
}